// Round 3
// baseline (67.459 us; speedup 1.0000x reference)
//
#include <hip/hip_runtime.h>
#include <hip/hip_bf16.h>

// Renderer interpolation: out[p, d] = sum_k bary[p,k] * attributes[faces[wrap(pix[p])][k], d]
// mask[p] = (pix[p] != -1)
// H=W=1024, D=32, F=100000, V=50000.
// 8 threads per pixel-chunk (float4 each); each thread processes TWO pixels
// (p and p+npix/2) for 2x memory-level parallelism on the 3-deep gather chain.
// Streaming traffic (pix, bary, out) uses nontemporal hints so L2 stays
// dedicated to the faces (1.2MB) + attributes (6.4MB) gather tables.

typedef float fvec4 __attribute__((ext_vector_type(4)));  // clang vector: ok for nontemporal builtins

__global__ __launch_bounds__(256) void Renderer_interp_kernel(
    const int* __restrict__ pix,      // (npix)
    const float* __restrict__ bary,   // (npix, 3)
    const int* __restrict__ faces,    // (F, 3)
    const float* __restrict__ attr,   // (V, 32)
    float* __restrict__ out,          // (npix, 32)
    float* __restrict__ mask,         // (npix) as float 0/1
    int npix, int F)
{
    int tid = blockIdx.x * blockDim.x + threadIdx.x;
    int half = npix >> 1;             // npix = 2^20, even
    int g = tid >> 3;                 // pixel-pair index
    int t = tid & 7;                  // d-chunk: covers d = 4t .. 4t+3
    if (g >= half) return;
    int p0 = g;
    int p1 = g + half;

    // ---- stage 1: pixel->face (streaming, nontemporal) ----
    int fraw0 = __builtin_nontemporal_load(&pix[p0]);
    int fraw1 = __builtin_nontemporal_load(&pix[p1]);
    int f0 = (fraw0 < 0) ? (fraw0 + F) : fraw0;   // mode='wrap': -1 -> F-1
    int f1 = (fraw1 < 0) ? (fraw1 + F) : fraw1;

    // ---- stage 2: face->vertices (cached; 1.2MB table) ----
    int b0 = 3 * f0, b1 = 3 * f1;
    int v00 = faces[b0 + 0], v01 = faces[b0 + 1], v02 = faces[b0 + 2];
    int v10 = faces[b1 + 0], v11 = faces[b1 + 1], v12 = faces[b1 + 2];

    // barycentric weights (streaming)
    float w00 = __builtin_nontemporal_load(&bary[3 * p0 + 0]);
    float w01 = __builtin_nontemporal_load(&bary[3 * p0 + 1]);
    float w02 = __builtin_nontemporal_load(&bary[3 * p0 + 2]);
    float w10 = __builtin_nontemporal_load(&bary[3 * p1 + 0]);
    float w11 = __builtin_nontemporal_load(&bary[3 * p1 + 1]);
    float w12 = __builtin_nontemporal_load(&bary[3 * p1 + 2]);

    // ---- stage 3: vertex->attributes (cached; 6.4MB table) ----
    const fvec4* A = reinterpret_cast<const fvec4*>(attr);
    fvec4 r00 = A[v00 * 8 + t];
    fvec4 r01 = A[v01 * 8 + t];
    fvec4 r02 = A[v02 * 8 + t];
    fvec4 r10 = A[v10 * 8 + t];
    fvec4 r11 = A[v11 * 8 + t];
    fvec4 r12 = A[v12 * 8 + t];

    fvec4 o0 = w00 * r00 + w01 * r01 + w02 * r02;
    fvec4 o1 = w10 * r10 + w11 * r11 + w12 * r12;

    // ---- output (streaming, nontemporal) ----
    fvec4* O = reinterpret_cast<fvec4*>(out);
    __builtin_nontemporal_store(o0, &O[(size_t)p0 * 8 + t]);
    __builtin_nontemporal_store(o1, &O[(size_t)p1 * 8 + t]);

    if (t == 0) {
        __builtin_nontemporal_store((fraw0 != -1) ? 1.0f : 0.0f, &mask[p0]);
        __builtin_nontemporal_store((fraw1 != -1) ? 1.0f : 0.0f, &mask[p1]);
    }
}

extern "C" void kernel_launch(void* const* d_in, const int* in_sizes, int n_in,
                              void* d_out, int out_size, void* d_ws, size_t ws_size,
                              hipStream_t stream) {
    const int*   pix   = (const int*)d_in[0];
    const float* bary  = (const float*)d_in[1];
    const int*   faces = (const int*)d_in[2];
    const float* attr  = (const float*)d_in[3];

    int npix = in_sizes[0];        // H*W = 1048576
    int F    = in_sizes[2] / 3;    // 100000

    float* out  = (float*)d_out;                      // (npix, 32)
    float* mask = (float*)d_out + (size_t)npix * 32;  // (npix,)

    int half = npix >> 1;
    int total = half * 8;
    int block = 256;
    int grid = (total + block - 1) / block;
    Renderer_interp_kernel<<<grid, block, 0, stream>>>(pix, bary, faces, attr,
                                                       out, mask, npix, F);
}